// Round 4
// baseline (100.822 us; speedup 1.0000x reference)
//
#include <hip/hip_runtime.h>

// Problem constants (reference: N=8192 queries, D=384, M=1024 docs)
#define N_Q   8192
#define DIM   384     // = 12 MFMA k-steps of 32
#define N_DOC 1024

typedef unsigned short ushort_t;
typedef __attribute__((ext_vector_type(8))) short bf16x8;
typedef __attribute__((ext_vector_type(4))) float f32x4;

__device__ __forceinline__ float bf2f(ushort_t u) {
    union { unsigned i; float f; } c; c.i = ((unsigned)u) << 16; return c.f;
}
__device__ __forceinline__ ushort_t f2bf(float f) {   // RNE
    union { float f; unsigned u; } c; c.f = f;
    unsigned r = c.u + 0x7FFF + ((c.u >> 16) & 1);
    return (ushort_t)(r >> 16);
}

// ---------------------------------------------------------------------------
// Kernel A: row-normalize emb_q -> nq (bf16). One wave per row (384 = 64*6).
// ---------------------------------------------------------------------------
__global__ __launch_bounds__(256) void k_normalize(const float* __restrict__ emb,
                                                   ushort_t* __restrict__ nqb) {
    int w    = (blockIdx.x * 256 + threadIdx.x) >> 6;   // row
    int lane = threadIdx.x & 63;
    const float* row = emb + (size_t)w * DIM;
    float v[6];
    float ss = 0.f;
#pragma unroll
    for (int r = 0; r < 6; ++r) { v[r] = row[lane + 64 * r]; ss += v[r] * v[r]; }
#pragma unroll
    for (int off = 32; off; off >>= 1) ss += __shfl_xor(ss, off);
    float inv = rsqrtf(ss);
    ushort_t* o = nqb + (size_t)w * DIM;
#pragma unroll
    for (int r = 0; r < 6; ++r) o[lane + 64 * r] = f2bf(v[r] * inv);
}

// ---------------------------------------------------------------------------
// Kernel B: per-doc weighted segment sum -> H[j,:] (bf16), fp32 accum.
// 8 waves per doc; wave w scans queries [w*1024, (w+1)*1024); partials
// combined in LDS in fixed wave order (bit-deterministic).
// ---------------------------------------------------------------------------
#define SS_WAVES 8
__global__ __launch_bounds__(512) void k_segsum(const ushort_t* __restrict__ nqb,
                                                const float* __restrict__ label,
                                                const int*   __restrict__ ids,
                                                ushort_t* __restrict__ Hb) {
    __shared__ float pacc[SS_WAVES][DIM];
    __shared__ float pden[SS_WAVES];
    int j    = blockIdx.x;
    int lane = threadIdx.x & 63;
    int w    = threadIdx.x >> 6;
    const int span = N_Q / SS_WAVES;          // 1024
    int q0 = w * span;

    float acc[6] = {0.f, 0.f, 0.f, 0.f, 0.f, 0.f};
    float den = 0.f;

    int idc = ids[q0 + lane];
    for (int base = q0; base < q0 + span; base += 64) {
        int nb = base + 64;
        int idn = (nb < q0 + span) ? ids[nb + lane] : -1;
        unsigned long long mask = __ballot(idc == j);
        while (mask) {
            int b = __builtin_ctzll(mask);
            mask &= mask - 1;
            int q = base + b;
            float lab = label[q];
            const ushort_t* r = nqb + (size_t)q * DIM;
#pragma unroll
            for (int t = 0; t < 6; ++t) acc[t] = fmaf(lab, bf2f(r[lane + 64 * t]), acc[t]);
            den += lab;
        }
        idc = idn;
    }
#pragma unroll
    for (int t = 0; t < 6; ++t) pacc[w][lane + 64 * t] = acc[t];
    if (lane == 0) pden[w] = den;
    __syncthreads();

    int d = threadIdx.x;
    if (d < DIM) {
        float s = 0.f, dn = 0.f;
#pragma unroll
        for (int ww = 0; ww < SS_WAVES; ++ww) { s += pacc[ww][d]; dn += pden[ww]; }
        float invd = (dn > 0.f) ? (1.f / dn) : 0.f;   // empty group -> 0 (never gathered)
        Hb[(size_t)j * DIM + d] = f2bf(s * invd);
    }
}

// ---------------------------------------------------------------------------
// Kernel C (fused GEMM + expand):
//   Block = 16 output rows. 4 waves; wave w owns cols [w*256, w*256+256).
//   Phase 1: T-slab[16][1024] = nq[rows] . H^T via MFMA 16x16x32, operands
//            read DIRECT from global (A: 12 KB -> L1; B = Hb: 768 KB -> L2),
//            1-step prefetch, no LDS, no barriers.
//   Phase 2: dump slab to LDS (64 KB), one barrier, gather-expand:
//            out[i, q] = slab[i, ids[q]], float4 stores (write-BW bound).
//   2 blocks/CU -> one block's MFMA overlaps the other's writes.
// ---------------------------------------------------------------------------
#define FROWS 16
__global__ __launch_bounds__(256, 2) void k_fused(const ushort_t* __restrict__ A,  // nq bf16 [N_Q][DIM]
                                                  const ushort_t* __restrict__ B,  // H  bf16 [N_DOC][DIM]
                                                  const int*      __restrict__ ids,
                                                  float*          __restrict__ out) {
    __shared__ float slab[FROWS][N_DOC];   // 64 KB
    int tid  = threadIdx.x;
    int lane = tid & 63, w = tid >> 6;
    int fr = lane & 15, kg = lane >> 4;
    int row0 = blockIdx.x * FROWS;

    const ushort_t* Ap = A + (size_t)(row0 + fr) * DIM + kg * 8;       // a-frag: row=fr, k=kg*8..
    const ushort_t* Bp = B + (size_t)(w * 256 + fr) * DIM + kg * 8;    // b-frag: col=fr, k=kg*8..

    f32x4 acc[16];
#pragma unroll
    for (int ni = 0; ni < 16; ++ni) acc[ni] = (f32x4)0.f;

    bf16x8 a_c = *(const bf16x8*)Ap;
    bf16x8 b_c[16];
#pragma unroll
    for (int ni = 0; ni < 16; ++ni) b_c[ni] = *(const bf16x8*)(Bp + (size_t)ni * 16 * DIM);

#pragma unroll
    for (int k0 = 0; k0 < DIM; k0 += 32) {
        bf16x8 a_n, b_n[16];
        if (k0 + 32 < DIM) {
            a_n = *(const bf16x8*)(Ap + k0 + 32);
#pragma unroll
            for (int ni = 0; ni < 16; ++ni)
                b_n[ni] = *(const bf16x8*)(Bp + (size_t)ni * 16 * DIM + k0 + 32);
        }
#pragma unroll
        for (int ni = 0; ni < 16; ++ni)
            acc[ni] = __builtin_amdgcn_mfma_f32_16x16x32_bf16(a_c, b_c[ni], acc[ni], 0, 0, 0);
        a_c = a_n;
#pragma unroll
        for (int ni = 0; ni < 16; ++ni) b_c[ni] = b_n[ni];
    }

    // prefetch all ids this thread needs (overlaps with dump + barrier)
    int4 idv[N_Q / 4 / 256];                      // 8
    const int4* id4 = (const int4*)ids;
#pragma unroll
    for (int it = 0; it < N_Q / 4 / 256; ++it) idv[it] = id4[it * 256 + tid];

    // dump: C/D layout col=lane&15, row=(lane>>4)*4+r  [m89]
#pragma unroll
    for (int ni = 0; ni < 16; ++ni)
#pragma unroll
        for (int r = 0; r < 4; ++r)
            slab[kg * 4 + r][w * 256 + ni * 16 + fr] = acc[ni][r];
    __syncthreads();

    // expand: 16 rows x 8192 cols, float4 stores
#pragma unroll
    for (int it = 0; it < N_Q / 4 / 256; ++it) {
        int q4 = it * 256 + tid;
        int4 id = idv[it];
#pragma unroll
        for (int r = 0; r < FROWS; ++r)
            ((float4*)(out + (size_t)(row0 + r) * N_Q))[q4] =
                make_float4(slab[r][id.x], slab[r][id.y], slab[r][id.z], slab[r][id.w]);
    }
}

// ---------------------------------------------------------------------------
extern "C" void kernel_launch(void* const* d_in, const int* in_sizes, int n_in,
                              void* d_out, int out_size, void* d_ws, size_t ws_size,
                              hipStream_t stream) {
    const float* emb   = (const float*)d_in[0];
    const float* label = (const float*)d_in[1];
    const int*   ids   = (const int*)d_in[2];
    float* out = (float*)d_out;

    // workspace: nqb bf16 [N_Q*DIM] | Hb bf16 [N_DOC*DIM]   (~7 MB)
    ushort_t* nqb = (ushort_t*)d_ws;
    ushort_t* Hb  = nqb + (size_t)N_Q * DIM;

    k_normalize<<<N_Q / 4, 256, 0, stream>>>(emb, nqb);
    k_segsum<<<N_DOC, 512, 0, stream>>>(nqb, label, ids, Hb);
    k_fused<<<N_Q / FROWS, 256, 0, stream>>>(nqb, Hb, ids, out);
}

// Round 6
// 78.986 us; speedup vs baseline: 1.2765x; 1.2765x over previous
//
#include <hip/hip_runtime.h>

// Problem constants (reference: N=8192 queries, D=384, M=1024 docs)
#define N_Q   8192
#define DIM   384     // = 12 MFMA k-steps of 32
#define N_DOC 1024

typedef unsigned short ushort_t;
typedef __attribute__((ext_vector_type(8))) short bf16x8;
typedef __attribute__((ext_vector_type(4))) float f32x4;
typedef __attribute__((ext_vector_type(4))) int i32x4;

__device__ __forceinline__ float bf2f(ushort_t u) {
    union { unsigned i; float f; } c; c.i = ((unsigned)u) << 16; return c.f;
}
__device__ __forceinline__ ushort_t f2bf(float f) {   // RNE
    union { float f; unsigned u; } c; c.f = f;
    unsigned r = c.u + 0x7FFF + ((c.u >> 16) & 1);
    return (ushort_t)(r >> 16);
}
__device__ __forceinline__ void gload_lds16(const void* g, void* l) {
    __builtin_amdgcn_global_load_lds((const __attribute__((address_space(1))) void*)g,
                                     (__attribute__((address_space(3))) void*)l, 16, 0, 0);
}

// ---------------------------------------------------------------------------
// Kernel A: row-normalize emb_q -> nq (bf16). One wave per row (384 = 64*6).
// ---------------------------------------------------------------------------
__global__ __launch_bounds__(256) void k_normalize(const float* __restrict__ emb,
                                                   ushort_t* __restrict__ nqb) {
    int w    = (blockIdx.x * 256 + threadIdx.x) >> 6;   // row
    int lane = threadIdx.x & 63;
    const float* row = emb + (size_t)w * DIM;
    float v[6];
    float ss = 0.f;
#pragma unroll
    for (int r = 0; r < 6; ++r) { v[r] = row[lane + 64 * r]; ss += v[r] * v[r]; }
#pragma unroll
    for (int off = 32; off; off >>= 1) ss += __shfl_xor(ss, off);
    float inv = rsqrtf(ss);
    ushort_t* o = nqb + (size_t)w * DIM;
#pragma unroll
    for (int r = 0; r < 6; ++r) o[lane + 64 * r] = f2bf(v[r] * inv);
}

// ---------------------------------------------------------------------------
// Kernel B: per-doc weighted segment sum -> H[j,:] (bf16), fp32 accum.
// 8 waves per doc; wave w scans queries [w*1024, (w+1)*1024); partials
// combined in LDS in fixed wave order (bit-deterministic).
// ---------------------------------------------------------------------------
#define SS_WAVES 8
__global__ __launch_bounds__(512) void k_segsum(const ushort_t* __restrict__ nqb,
                                                const float* __restrict__ label,
                                                const int*   __restrict__ ids,
                                                ushort_t* __restrict__ Hb) {
    __shared__ float pacc[SS_WAVES][DIM];
    __shared__ float pden[SS_WAVES];
    int j    = blockIdx.x;
    int lane = threadIdx.x & 63;
    int w    = threadIdx.x >> 6;
    const int span = N_Q / SS_WAVES;          // 1024
    int q0 = w * span;

    float acc[6] = {0.f, 0.f, 0.f, 0.f, 0.f, 0.f};
    float den = 0.f;

    int idc = ids[q0 + lane];
    for (int base = q0; base < q0 + span; base += 64) {
        int nb = base + 64;
        int idn = (nb < q0 + span) ? ids[nb + lane] : -1;
        unsigned long long mask = __ballot(idc == j);
        while (mask) {
            int b = __builtin_ctzll(mask);
            mask &= mask - 1;
            int q = base + b;
            float lab = label[q];
            const ushort_t* r = nqb + (size_t)q * DIM;
#pragma unroll
            for (int t = 0; t < 6; ++t) acc[t] = fmaf(lab, bf2f(r[lane + 64 * t]), acc[t]);
            den += lab;
        }
        idc = idn;
    }
#pragma unroll
    for (int t = 0; t < 6; ++t) pacc[w][lane + 64 * t] = acc[t];
    if (lane == 0) pden[w] = den;
    __syncthreads();

    int d = threadIdx.x;
    if (d < DIM) {
        float s = 0.f, dn = 0.f;
#pragma unroll
        for (int ww = 0; ww < SS_WAVES; ++ww) { s += pacc[ww][d]; dn += pden[ww]; }
        float invd = (dn > 0.f) ? (1.f / dn) : 0.f;   // empty group -> 0 (never gathered)
        Hb[(size_t)j * DIM + d] = f2bf(s * invd);
    }
}

// ---------------------------------------------------------------------------
// Kernel C: T[i,j] = nq[i,:] . H[j,:]  -- bf16 MFMA 16x16x32, fp32 accum,
// bf16 T output. 128x128 tile, 4 waves (2x2), wave 4x4 fragments. BK=64.
// global_load_lds width-16 staging, linear LDS dest + XOR-swizzled global
// source; fragment ds_read_b128 applies the same XOR -> ~2-way banks.
// ---------------------------------------------------------------------------
#define BM 128
#define BN 128
#define BK 64

__global__ __launch_bounds__(256) void k_gemm(const ushort_t* __restrict__ A,  // nq bf16 [N_Q][DIM]
                                              const ushort_t* __restrict__ B,  // H  bf16 [N_DOC][DIM]
                                              ushort_t* __restrict__ Tb) {     // bf16 [N_Q][N_DOC]
    __shared__ ushort_t As[BM * BK];   // 16 KB, swizzled granules
    __shared__ ushort_t Bs[BN * BK];
    int tid  = threadIdx.x;
    int lane = tid & 63, wid = tid >> 6;
    int wr = wid >> 1, wc = wid & 1;             // 2x2 wave grid
    int row0 = blockIdx.y * BM, col0 = blockIdx.x * BN;
    int fr = lane & 15, kg = lane >> 4;

    f32x4 acc[4][4];
#pragma unroll
    for (int i = 0; i < 4; ++i)
#pragma unroll
        for (int j = 0; j < 4; ++j) acc[i][j] = (f32x4)0.f;

    for (int k0 = 0; k0 < DIM; k0 += BK) {
#pragma unroll
        for (int r = 0; r < 4; ++r) {
            int flat = r * 256 + tid;
            int row = flat >> 3, gd = flat & 7;
            int gs = gd ^ (row & 7);                     // involutive source swizzle
            int wbase = (r * 256 + wid * 64) * 8;        // wave-uniform LDS elem base
            gload_lds16(A + (size_t)(row0 + row) * DIM + k0 + gs * 8, &As[wbase]);
            gload_lds16(B + (size_t)(col0 + row) * DIM + k0 + gs * 8, &Bs[wbase]);
        }
        __syncthreads();

#pragma unroll
        for (int ks = 0; ks < 2; ++ks) {                 // two k=32 steps per BK=64
            bf16x8 a[4], b[4];
#pragma unroll
            for (int mi = 0; mi < 4; ++mi) {
                int m = wr * 64 + mi * 16 + fr;
                a[mi] = *(const bf16x8*)&As[m * 64 + (((ks * 4 + kg) ^ (m & 7)) << 3)];
            }
#pragma unroll
            for (int ni = 0; ni < 4; ++ni) {
                int n = wc * 64 + ni * 16 + fr;
                b[ni] = *(const bf16x8*)&Bs[n * 64 + (((ks * 4 + kg) ^ (n & 7)) << 3)];
            }
#pragma unroll
            for (int mi = 0; mi < 4; ++mi)
#pragma unroll
                for (int ni = 0; ni < 4; ++ni)
                    acc[mi][ni] = __builtin_amdgcn_mfma_f32_16x16x32_bf16(a[mi], b[ni], acc[mi][ni], 0, 0, 0);
        }
        __syncthreads();
    }

    // C/D layout: col = lane&15, row = (lane>>4)*4 + reg   [m89]
#pragma unroll
    for (int mi = 0; mi < 4; ++mi)
#pragma unroll
        for (int ni = 0; ni < 4; ++ni)
#pragma unroll
            for (int r = 0; r < 4; ++r)
                Tb[(size_t)(row0 + wr * 64 + mi * 16 + kg * 4 + r) * N_DOC
                   + col0 + wc * 64 + ni * 16 + fr] = f2bf(acc[mi][ni][r]);
}

// ---------------------------------------------------------------------------
// Kernel D: out[i,q] = T[i, ids[q]].  8 rows/block (1024 blocks = 4/CU).
// ids held in registers; 8 bf16 T-rows converted to f32 in 32 KB LDS;
// non-temporal f32x4 stores (write-BW bound, no L2 pollution).
// ---------------------------------------------------------------------------
#define EROWS 8
__global__ __launch_bounds__(256) void k_expand(const ushort_t* __restrict__ Tb,
                                                const int*      __restrict__ ids,
                                                float*          __restrict__ out) {
    __shared__ float trow[EROWS * N_DOC];   // 32 KB
    int tid = threadIdx.x;
    int i0  = blockIdx.x * EROWS;

    // ids -> registers (8 x i32x4 per thread)
    i32x4 idv[N_Q / 4 / 256];
    const i32x4* id4 = (const i32x4*)ids;
#pragma unroll
    for (int it = 0; it < N_Q / 4 / 256; ++it) idv[it] = id4[it * 256 + tid];

    // stage 8 bf16 rows -> f32 LDS (1024 chunks of 16 B)
    const bf16x8* Tv = (const bf16x8*)(Tb + (size_t)i0 * N_DOC);
#pragma unroll
    for (int c = 0; c < 4; ++c) {
        int chunk = c * 256 + tid;
        bf16x8 v = Tv[chunk];
        f32x4 lo = { bf2f((ushort_t)v[0]), bf2f((ushort_t)v[1]), bf2f((ushort_t)v[2]), bf2f((ushort_t)v[3]) };
        f32x4 hi = { bf2f((ushort_t)v[4]), bf2f((ushort_t)v[5]), bf2f((ushort_t)v[6]), bf2f((ushort_t)v[7]) };
        *(f32x4*)&trow[chunk * 8]     = lo;
        *(f32x4*)&trow[chunk * 8 + 4] = hi;
    }
    __syncthreads();

#pragma unroll
    for (int it = 0; it < N_Q / 4 / 256; ++it) {   // 8 iterations over q
        int q4 = it * 256 + tid;
        i32x4 id = idv[it];
#pragma unroll
        for (int r = 0; r < EROWS; ++r) {
            const float* tr = &trow[r * N_DOC];
            f32x4 v = { tr[id.x], tr[id.y], tr[id.z], tr[id.w] };
            __builtin_nontemporal_store(v, (f32x4*)(out + (size_t)(i0 + r) * N_Q) + q4);
        }
    }
}

// ---------------------------------------------------------------------------
extern "C" void kernel_launch(void* const* d_in, const int* in_sizes, int n_in,
                              void* d_out, int out_size, void* d_ws, size_t ws_size,
                              hipStream_t stream) {
    const float* emb   = (const float*)d_in[0];
    const float* label = (const float*)d_in[1];
    const int*   ids   = (const int*)d_in[2];
    float* out = (float*)d_out;

    // workspace: nqb bf16 [N_Q*DIM] | Hb bf16 [N_DOC*DIM] | Tb bf16 [N_Q*N_DOC]
    ushort_t* nqb = (ushort_t*)d_ws;
    ushort_t* Hb  = nqb + (size_t)N_Q * DIM;
    ushort_t* Tb  = Hb + (size_t)N_DOC * DIM;

    k_normalize<<<N_Q / 4, 256, 0, stream>>>(emb, nqb);
    k_segsum<<<N_DOC, 512, 0, stream>>>(nqb, label, ids, Hb);
    k_gemm<<<dim3(N_DOC / BN, N_Q / BM), 256, 0, stream>>>(nqb, Hb, Tb);
    k_expand<<<N_Q / EROWS, 256, 0, stream>>>(Tb, ids, out);
}